// Round 9
// baseline (447.021 us; speedup 1.0000x reference)
//
#include <hip/hip_runtime.h>

// HGIN_classifier: two relational-GIN layers (R=2), ReLU between.
// R23: replace bucketB/bscan/bucketC CSR build with flat counting sort.
// R22 post-mortem: aggregate profiled at 84us, 4.9TB/s effective L2/L3
// gather service (fabric floor; segment-wave reshape was -9us vs R14's
// per-node form -> REVERTED to per-node). gemm+aggregate = 163us; total
// 335.7 -> ~172us hides in the CSR build + cvt + gather2. bucketB alone
// does 400k global atomics on 512 addresses (782 serialized hits each) +
// an 8MB ebuf round-trip + double-reads. New sort: count into 200k per-seg
// counters (8 hits/addr, contention-free) -> 391-block local scan ->
// 1-block top scan -> finalize(off,cur) -> scatter via per-seg cursors.
// No ebuf. Predicted total 335.7 -> ~255-295; >=320 falsifies (cost is
// elsewhere: launch gaps / cvt / gather2).
// Pipeline: zero_cnt -> count_edges -> scan_local -> bscan2 -> finalize
//           -> scatter_edges ; cvt_all -> aggregate -> gemm_mfma -> gather2

typedef _Float16 f16;
typedef _Float16 f16x2 __attribute__((ext_vector_type(2)));
typedef _Float16 f16x4 __attribute__((ext_vector_type(4)));
typedef _Float16 f16x8 __attribute__((ext_vector_type(8)));
typedef float    f32x4 __attribute__((ext_vector_type(4)));
typedef __attribute__((address_space(3))) void       as3_void;
typedef __attribute__((address_space(1))) const void as1_cvoid;

constexpr int NN   = 100000;
constexpr int NR   = NN * 2;          // (node, relation) segments
constexpr int NBK  = (NR + 511) / 512; // 391 scan blocks

__global__ void zero_cnt(int* __restrict__ cnt) {
  int g = blockIdx.x * 256 + threadIdx.x;
  if (g < NR) cnt[g] = 0;
}

__global__ void count_edges(const int* __restrict__ dst, const int* __restrict__ et,
                            int* __restrict__ cnt, int E) {
  int e = blockIdx.x * 256 + threadIdx.x;
  if (e < E) atomicAdd(&cnt[dst[e] * 2 + et[e]], 1);
}

// Per-512-segment block: exclusive scan of cnt -> pre, block total -> bsum.
__global__ void scan_local(const int* __restrict__ cnt, int* __restrict__ pre,
                           int* __restrict__ bsum) {
  __shared__ int s[512];
  int b = blockIdx.x, t = threadIdx.x;
  int g = b * 512 + t;
  int v = (g < NR) ? cnt[g] : 0;
  s[t] = v;
  __syncthreads();
  #pragma unroll
  for (int o = 1; o < 512; o <<= 1) {
    int u = (t >= o) ? s[t - o] : 0;
    __syncthreads();
    s[t] += u;
    __syncthreads();
  }
  if (g < NR) pre[g] = s[t] - v;
  if (t == 511) bsum[b] = s[t];
}

// One block: exclusive scan of the 391 block sums.
__global__ void bscan2(const int* __restrict__ bsum, int* __restrict__ bbase) {
  __shared__ int s[512];
  int t = threadIdx.x;
  int v = (t < NBK) ? bsum[t] : 0;
  s[t] = v;
  __syncthreads();
  #pragma unroll
  for (int o = 1; o < 512; o <<= 1) {
    int u = (t >= o) ? s[t - o] : 0;
    __syncthreads();
    s[t] += u;
    __syncthreads();
  }
  if (t < NBK) bbase[t] = s[t] - v;
}

__global__ void finalize(const int* __restrict__ pre, const int* __restrict__ bbase,
                         int* __restrict__ off, int* __restrict__ cur, int E) {
  int g = blockIdx.x * 256 + threadIdx.x;
  if (g < NR) {
    int o = bbase[g >> 9] + pre[g];
    off[g] = o;
    cur[g] = o;
  } else if (g == NR) {
    off[NR] = E;
  }
}

__global__ void scatter_edges(const int* __restrict__ src, const int* __restrict__ dst,
                              const int* __restrict__ et, int* __restrict__ cur,
                              int* __restrict__ srcs, int E) {
  int e = blockIdx.x * 256 + threadIdx.x;
  if (e < E) {
    int seg = dst[e] * 2 + et[e];
    int p = atomicAdd(&cur[seg], 1);
    srcs[p] = src[e];
  }
}

// merged cast: x -> f16 and W1 -> k-step-major f16 repack.
// w1t[ks][n][ki] = f16(W[ks*32+ki][n]).
__global__ void cvt_all(const float4* __restrict__ xf, f16* __restrict__ xh,
                        const float* __restrict__ w1s, const float* __restrict__ w1r,
                        f16* __restrict__ w1t, int n4) {
  int i = blockIdx.x * blockDim.x + threadIdx.x;
  if (i < n4) {
    float4 v = xf[i];
    f16x4 h;
    h.x = (f16)v.x; h.y = (f16)v.y; h.z = (f16)v.z; h.w = (f16)v.w;
    *(f16x4*)(xh + (size_t)i * 4) = h;
  } else {
    int id = i - n4;
    if (id < 12 * 256 * 32) {
      int ks = id >> 13, rem = id & 8191;
      int n = rem >> 5, ki = rem & 31;
      int k = ks * 32 + ki;
      float v = (k < 128) ? w1s[k * 256 + n] : w1r[(k - 128) * 256 + n];
      w1t[id] = (f16)v;
    }
  }
}

// [R14 form restored] One wave per node. Lane-half h=lane>>5 processes edge
// e+h: one instruction loads 2 rows (32 lanes x f16x4 = 256B each). Halves
// merged via shfl_xor(32).
__global__ void aggregate(const f16* __restrict__ xh, const int* __restrict__ off,
                          const int* __restrict__ srcs, f16* __restrict__ aggh) {
  int w = (blockIdx.x * blockDim.x + threadIdx.x) >> 6;
  if (w >= NN) return;
  int lane = threadIdx.x & 63;
  int h = lane >> 5, c = lane & 31;
  int e0 = off[2 * w];
  int e1 = off[2 * w + 1];
  int e2 = off[2 * w + 2];
  float ax = 0.f, ay = 0.f, az = 0.f, aw = 0.f;
  float bx = 0.f, by = 0.f, bz = 0.f, bw = 0.f;

  int e = e0;
  for (; e + 7 < e1; e += 8) {
    f16x4 v0 = *(const f16x4*)(xh + (long)srcs[e     + h] * 128 + c * 4);
    f16x4 v1 = *(const f16x4*)(xh + (long)srcs[e + 2 + h] * 128 + c * 4);
    f16x4 v2 = *(const f16x4*)(xh + (long)srcs[e + 4 + h] * 128 + c * 4);
    f16x4 v3 = *(const f16x4*)(xh + (long)srcs[e + 6 + h] * 128 + c * 4);
    ax += (float)v0.x + (float)v1.x + (float)v2.x + (float)v3.x;
    ay += (float)v0.y + (float)v1.y + (float)v2.y + (float)v3.y;
    az += (float)v0.z + (float)v1.z + (float)v2.z + (float)v3.z;
    aw += (float)v0.w + (float)v1.w + (float)v2.w + (float)v3.w;
  }
  for (; e + 1 < e1; e += 2) {
    f16x4 v = *(const f16x4*)(xh + (long)srcs[e + h] * 128 + c * 4);
    ax += (float)v.x; ay += (float)v.y; az += (float)v.z; aw += (float)v.w;
  }
  if (e < e1) {
    f16x4 v = *(const f16x4*)(xh + (long)srcs[e] * 128 + c * 4);
    if (h == 0) { ax += (float)v.x; ay += (float)v.y; az += (float)v.z; aw += (float)v.w; }
  }
  e = e1;
  for (; e + 7 < e2; e += 8) {
    f16x4 v0 = *(const f16x4*)(xh + (long)srcs[e     + h] * 128 + c * 4);
    f16x4 v1 = *(const f16x4*)(xh + (long)srcs[e + 2 + h] * 128 + c * 4);
    f16x4 v2 = *(const f16x4*)(xh + (long)srcs[e + 4 + h] * 128 + c * 4);
    f16x4 v3 = *(const f16x4*)(xh + (long)srcs[e + 6 + h] * 128 + c * 4);
    bx += (float)v0.x + (float)v1.x + (float)v2.x + (float)v3.x;
    by += (float)v0.y + (float)v1.y + (float)v2.y + (float)v3.y;
    bz += (float)v0.z + (float)v1.z + (float)v2.z + (float)v3.z;
    bw += (float)v0.w + (float)v1.w + (float)v2.w + (float)v3.w;
  }
  for (; e + 1 < e2; e += 2) {
    f16x4 v = *(const f16x4*)(xh + (long)srcs[e + h] * 128 + c * 4);
    bx += (float)v.x; by += (float)v.y; bz += (float)v.z; bw += (float)v.w;
  }
  if (e < e2) {
    f16x4 v = *(const f16x4*)(xh + (long)srcs[e] * 128 + c * 4);
    if (h == 0) { bx += (float)v.x; by += (float)v.y; bz += (float)v.z; bw += (float)v.w; }
  }

  ax += __shfl_xor(ax, 32); ay += __shfl_xor(ay, 32);
  az += __shfl_xor(az, 32); aw += __shfl_xor(aw, 32);
  bx += __shfl_xor(bx, 32); by += __shfl_xor(by, 32);
  bz += __shfl_xor(bz, 32); bw += __shfl_xor(bw, 32);

  f16* row = aggh + (long)w * 256;
  f16x4 o;
  if (h == 0) {
    o.x = (f16)ax; o.y = (f16)ay; o.z = (f16)az; o.w = (f16)aw;
    *(f16x4*)(row + c * 4) = o;
  } else {
    o.x = (f16)bx; o.y = (f16)by; o.z = (f16)bz; o.w = (f16)bw;
    *(f16x4*)(row + 128 + c * 4) = o;
  }
}

// Fused layer-1 GEMM (f16 MFMA) + layer-2 transform epilogue.
// [R14 — best measured: 79.5us, VGPR 80, 24.6KB LDS, 6 blocks/CU]
// 32-row tile: A (32r x 384k = 24 KB) staged upfront via global_load_lds as
// 12 slabs x 2 KB; wave wv issues 6 DMA instrs ((slab,half) pairs). ONE
// barrier, then barrier-free unrolled K-loop: A from ds_read_b128 (XOR chunk
// swizzle, conflict-free), B direct from L2.
// Grid 3125 (NN/32 exact). 4 waves, wave = 32r x 64c (acc 2x4 = 32 VGPR).
// Fragment layouts (m89/m120-verified): A: m=lane&15, k=quad*8+j;
// B: n=lane&15, k=quad*8+j; C/D: col=lane&15, row=quad*4+reg.
__global__ __launch_bounds__(256) void gemm_mfma(
    const f16* __restrict__ xh, const f16* __restrict__ aggh,
    const f16* __restrict__ w1t,
    const float* __restrict__ b1, const float* __restrict__ w2s,
    const float* __restrict__ w2r, const float* __restrict__ b2,
    float* __restrict__ z2, float* __restrict__ out) {
  __shared__ __align__(16) f16 Ash[12 * 1024];    // 12 slabs x 2 KB = 24 KB
  float (*zbuf)[32][6] = (float (*)[32][6])(void*)Ash;  // aliased (3 KB)
  const int t = threadIdx.x;
  const int lane = t & 63, wv = t >> 6;
  const int ml = lane & 15, quad = lane >> 4;
  const int cphi = quad ^ ((ml >> 1) & 3);        // swizzled chunk for frags
  const long rowBase = (long)blockIdx.x * 32;

  // ---- upfront A staging: 24 wave-level DMA instrs, 6 per wave.
  #pragma unroll
  for (int i = 0; i < 6; ++i) {
    int g = wv * 6 + i;
    int slab = g >> 1, half = g & 1;
    int s = half * 64 + lane;
    int r = s >> 2;
    int cl = (s & 3) ^ ((r >> 1) & 3);
    long grow = rowBase + r;
    const f16* ap = (slab < 4)
        ? (xh + grow * 128 + slab * 32 + cl * 8)
        : (aggh + grow * 256 + (slab - 4) * 32 + cl * 8);
    __builtin_amdgcn_global_load_lds((const as1_cvoid*)ap,
                                     (as3_void*)&Ash[slab * 1024 + half * 512],
                                     16, 0, 0);
  }
  __syncthreads();                                  // drains DMA + barrier

  // ---- barrier-free K-loop
  const f16* bwv = w1t + (long)(wv * 64 + ml) * 32 + quad * 8;
  f32x4 acc[2][4];
  #pragma unroll
  for (int mt = 0; mt < 2; ++mt)
    #pragma unroll
    for (int nt = 0; nt < 4; ++nt) acc[mt][nt] = (f32x4)(0.f);

  #pragma unroll
  for (int ks = 0; ks < 12; ++ks) {
    f16x8 af[2], bf[4];
    #pragma unroll
    for (int nt = 0; nt < 4; ++nt)
      bf[nt] = *(const f16x8*)(bwv + (long)ks * 8192 + nt * 16 * 32);
    #pragma unroll
    for (int mt = 0; mt < 2; ++mt)
      af[mt] = *(const f16x8*)&Ash[ks * 1024 + ((mt * 16 + ml) * 4 + cphi) * 8];
    #pragma unroll
    for (int mt = 0; mt < 2; ++mt)
      #pragma unroll
      for (int nt = 0; nt < 4; ++nt)
        acc[mt][nt] = __builtin_amdgcn_mfma_f32_16x16x32_f16(af[mt], bf[nt],
                                                             acc[mt][nt], 0, 0, 0);
  }
  __syncthreads();   // all Ash reads done before zbuf (aliased) writes

  // Epilogue: h = relu(acc + b1[col]); 6 dots over this wave's 64 cols;
  // reduce over the 16 ml-lanes; partials to zbuf[wv] (aliased onto Ash).
  #pragma unroll
  for (int mt = 0; mt < 2; ++mt) {
    float z[4][6];
    #pragma unroll
    for (int rr = 0; rr < 4; ++rr)
      #pragma unroll
      for (int p = 0; p < 6; ++p) z[rr][p] = 0.f;
    #pragma unroll
    for (int nt = 0; nt < 4; ++nt) {
      int col = wv * 64 + nt * 16 + ml;
      float bb = b1[col];
      float wA = w2r[col * 2 + 0];
      float wB = w2r[col * 2 + 1];
      float wC = w2r[512 + col * 2 + 0];
      float wD = w2r[512 + col * 2 + 1];
      float wE = w2s[col * 2 + 0];
      float wF = w2s[col * 2 + 1];
      #pragma unroll
      for (int rr = 0; rr < 4; ++rr) {
        float hh = acc[mt][nt][rr] + bb;
        hh = hh > 0.f ? hh : 0.f;
        z[rr][0] = fmaf(hh, wA, z[rr][0]);
        z[rr][1] = fmaf(hh, wB, z[rr][1]);
        z[rr][2] = fmaf(hh, wC, z[rr][2]);
        z[rr][3] = fmaf(hh, wD, z[rr][3]);
        z[rr][4] = fmaf(hh, wE, z[rr][4]);
        z[rr][5] = fmaf(hh, wF, z[rr][5]);
      }
    }
    #pragma unroll
    for (int rr = 0; rr < 4; ++rr)
      #pragma unroll
      for (int p = 0; p < 6; ++p) {
        float v = z[rr][p];
        v += __shfl_xor(v, 1);
        v += __shfl_xor(v, 2);
        v += __shfl_xor(v, 4);
        v += __shfl_xor(v, 8);
        if (ml == 0) zbuf[wv][mt * 16 + quad * 4 + rr][p] = v;
      }
  }
  __syncthreads();
  if (t < 192) {
    int r = t / 6, p = t % 6;
    long grow = rowBase + r;
    float v = zbuf[0][r][p] + zbuf[1][r][p] + zbuf[2][r][p] + zbuf[3][r][p];
    if (p < 4) z2[grow * 4 + p] = v;
    else       out[grow * 2 + (p - 4)] = v + b2[p - 4];
  }
}

// 4 lanes per node: lane sub handles every-4th edge; reduce over sub.
__global__ void gather2(const float* __restrict__ z2, const int* __restrict__ off,
                        const int* __restrict__ srcs, float* __restrict__ out) {
  int tid = blockIdx.x * blockDim.x + threadIdx.x;
  int n = tid >> 2;
  if (n >= NN) return;
  int sub = tid & 3;
  int e0 = off[2 * n];
  int e1 = off[2 * n + 1];
  int e2 = off[2 * n + 2];
  float o0 = 0.f, o1 = 0.f;
  for (int e = e0 + sub; e < e1; e += 4) {
    float2 v = *(const float2*)(z2 + (long)srcs[e] * 4);
    o0 += v.x; o1 += v.y;
  }
  for (int e = e1 + sub; e < e2; e += 4) {
    float2 v = *(const float2*)(z2 + (long)srcs[e] * 4 + 2);
    o0 += v.x; o1 += v.y;
  }
  o0 += __shfl_xor(o0, 1); o1 += __shfl_xor(o1, 1);
  o0 += __shfl_xor(o0, 2); o1 += __shfl_xor(o1, 2);
  if (sub == 0) {
    out[n * 2 + 0] += o0;
    out[n * 2 + 1] += o1;
  }
}

extern "C" void kernel_launch(void* const* d_in, const int* in_sizes, int n_in,
                              void* d_out, int out_size, void* d_ws, size_t ws_size,
                              hipStream_t stream) {
  const float* x   = (const float*)d_in[0];
  const int*   ei  = (const int*)d_in[1];
  const int*   et  = (const int*)d_in[2];
  const float* w1s = (const float*)d_in[3];
  const float* w1r = (const float*)d_in[4];
  const float* b1  = (const float*)d_in[5];
  const float* w2s = (const float*)d_in[6];
  const float* w2r = (const float*)d_in[7];
  const float* b2  = (const float*)d_in[8];
  float* out = (float*)d_out;
  const int E = in_sizes[2];
  const int* src = ei;
  const int* dst = ei + E;

  f16*   aggh = (f16*)d_ws;                      // NN*256 f16   (51.2 MB)
  f16*   xh   = aggh + (size_t)NN * 256;         // NN*128 f16   (25.6 MB)
  f16*   w1t  = xh + (size_t)NN * 128;           // 12*256*32 f16 (0.2 MB)
  float* z2   = (float*)(w1t + 12 * 256 * 32);   // NN*4 f32     (1.6 MB)
  int*   srcs = (int*)(z2 + (size_t)NN * 4);     // E int        (6.4 MB)
  int*   off  = srcs + E;                        // NR+1 int     (0.8 MB)
  int*   cnt  = off + NR + 1;                    // NR int       (0.8 MB)
  int*   pre  = cnt + NR;                        // NR int       (0.8 MB)
  int*   cur  = pre + NR;                        // NR int       (0.8 MB)
  int*   bsum = cur + NR;                        // NBK int
  int*   bbase = bsum + NBK;                     // NBK int

  int eblk = (E + 255) / 256;
  zero_cnt<<<(NR + 255) / 256, 256, 0, stream>>>(cnt);
  count_edges<<<eblk, 256, 0, stream>>>(dst, et, cnt, E);
  scan_local<<<NBK, 512, 0, stream>>>(cnt, pre, bsum);
  bscan2<<<1, 512, 0, stream>>>(bsum, bbase);
  finalize<<<(NR + 256) / 256, 256, 0, stream>>>(pre, bbase, off, cur, E);
  scatter_edges<<<eblk, 256, 0, stream>>>(src, dst, et, cur, srcs, E);

  int n4 = NN * 128 / 4;
  int ncvt = n4 + 12 * 256 * 32;
  cvt_all<<<(ncvt + 255) / 256, 256, 0, stream>>>((const float4*)x, xh,
                                                  w1s, w1r, w1t, n4);

  aggregate<<<(NN * 64 + 255) / 256, 256, 0, stream>>>(xh, off, srcs, aggh);

  gemm_mfma<<<NN / 32, 256, 0, stream>>>(xh, aggh, w1t, b1, w2s, w2r, b2,
                                         z2, out);

  gather2<<<(NN * 4 + 255) / 256, 256, 0, stream>>>(z2, off, srcs, out);
}